// Round 5
// baseline (354.011 us; speedup 1.0000x reference)
//
#include <hip/hip_runtime.h>

// MergeAdapter: out = x + Up_n(relu(Down_n(x))), merged expert weights.
// N=16, S=2048, H=1024, Kexp=8, D=256. fp32 in/out, bf16 MFMA internally.
//
// Round 5: barrier-free phase 2. Round 4 showed MfmaUtil 9.6 / VALU 8.9 /
// HBM 30% — nothing saturated => barrier/latency-bound at 1 block/CU.
// Phase 2 now loads Wu B-fragments straight from global into registers
// (L2-hot via XCD batch swizzle), reads residual + writes out with NO
// __syncthreads after the single post-R barrier: 8 waves run free and
// keep a continuous memory stream. Phase 1 (x-HBM-bound, ~22 us) kept:
// dbuf BK=64, XOR-swizzled LDS.

typedef unsigned short u16;
typedef __bf16 bf16x8 __attribute__((ext_vector_type(8)));
typedef float f32x4 __attribute__((ext_vector_type(4)));

__device__ __forceinline__ u16 f2bf(float f) {
    union { float f; unsigned int i; } v; v.f = f;
    unsigned int r = v.i + 0x7fffu + ((v.i >> 16) & 1u);  // RNE
    return (u16)(r >> 16);
}

__device__ __forceinline__ void gload_lds16(const u16* g, u16* l) {
    __builtin_amdgcn_global_load_lds(
        (const __attribute__((address_space(1))) void*)g,
        (__attribute__((address_space(3))) void*)l,
        16, 0, 0);
}

__device__ __forceinline__ void store8(u16* dst, float4 a, float4 b) {
    union { uint4 u; u16 s[8]; } cv;
    cv.s[0]=f2bf(a.x); cv.s[1]=f2bf(a.y); cv.s[2]=f2bf(a.z); cv.s[3]=f2bf(a.w);
    cv.s[4]=f2bf(b.x); cv.s[5]=f2bf(b.y); cv.s[6]=f2bf(b.z); cv.s[7]=f2bf(b.w);
    *(uint4*)dst = cv.u;
}

// ---------------------------------------------------------------------------
// Kernel 0: merge weights + biases (fp32 in -> bf16 weights / fp32 biases).
// ---------------------------------------------------------------------------
__global__ __launch_bounds__(256)
void merge_kernel(const float* __restrict__ prob,
                  const float* __restrict__ w_down, const float* __restrict__ b_down,
                  const float* __restrict__ w_up,   const float* __restrict__ b_up,
                  u16* __restrict__ Wd, u16* __restrict__ Wu,
                  float* __restrict__ bd, float* __restrict__ bu)
{
    __shared__ float sp[128];          // prob (16 x 8)
    const int tid = threadIdx.x;
    if (tid < 128) sp[tid] = prob[tid];
    __syncthreads();

    const int bid = blockIdx.x;
    const int E = 256 * 1024;

    if (bid < 256) {
        int v = bid * 256 + tid;       // 0..65535 vector slots (8 elems each)
        const bool down = (v < 32768);
        const int vv = down ? v : (v - 32768);
        const float* W = down ? w_down : w_up;
        u16* O = down ? Wd : Wu;
        const size_t e = (size_t)vv * 8;

        float wf[8][8];
        #pragma unroll
        for (int k = 0; k < 8; ++k) {
            const float4 f0 = *(const float4*)(W + (size_t)k * E + e);
            const float4 f1 = *(const float4*)(W + (size_t)k * E + e + 4);
            wf[k][0] = f0.x; wf[k][1] = f0.y; wf[k][2] = f0.z; wf[k][3] = f0.w;
            wf[k][4] = f1.x; wf[k][5] = f1.y; wf[k][6] = f1.z; wf[k][7] = f1.w;
        }
        for (int n = 0; n < 16; ++n) {
            float a[8] = {0.f,0.f,0.f,0.f,0.f,0.f,0.f,0.f};
            #pragma unroll
            for (int k = 0; k < 8; ++k) {
                const float p = sp[n * 8 + k];
                #pragma unroll
                for (int j = 0; j < 8; ++j) a[j] = fmaf(p, wf[k][j], a[j]);
            }
            union { uint4 u; u16 s[8]; } ov;
            #pragma unroll
            for (int j = 0; j < 8; ++j) ov.s[j] = f2bf(a[j]);
            *(uint4*)(O + (size_t)n * E + e) = ov.u;
        }
    } else {
        int idx = (bid - 256) * 256 + tid;   // 0..20479
        if (idx < 16 * 256) {
            const int n = idx >> 8, d = idx & 255;
            float s = 0.f;
            #pragma unroll
            for (int k = 0; k < 8; ++k)
                s = fmaf(sp[n * 8 + k], b_down[k * 256 + d], s);
            bd[idx] = s;
        } else {
            const int i2 = idx - 4096;
            const int n = i2 >> 10, h = i2 & 1023;
            float s = 0.f;
            #pragma unroll
            for (int k = 0; k < 8; ++k)
                s = fmaf(sp[n * 8 + k], b_up[k * 1024 + h], s);
            bu[i2] = s;
        }
    }
}

// ---------------------------------------------------------------------------
// Fused adapter kernel.
// ---------------------------------------------------------------------------
__global__ __launch_bounds__(512, 2)
void fused_adapter(const float* __restrict__ x, const u16* __restrict__ Wd,
                   const u16* __restrict__ Wu, const float* __restrict__ bd,
                   const float* __restrict__ bu, float* __restrict__ out)
{
    __shared__ __align__(16) u16 lds0[32768];   // 64 KB: p1 bufB, then Rs
    __shared__ __align__(16) u16 lds1[32768];   // 64 KB: p1 bufA

    const int tid  = threadIdx.x;
    const int lane = tid & 63;
    const int wave = tid >> 6;               // 0..7
    const int quad = lane >> 4, rl = lane & 15;
    const int rxl  = rl & 7;

    // swizzle: each batch's 16 M-blocks share one XCD -> Wd/Wu L2-hot
    const int id = blockIdx.x;               // 0..255
    const int r4 = id & 15;
    const int batch = (r4 & 7) * 2 + (r4 >> 3);
    const int mblk  = id >> 4;               // 0..15

    const float* xb  = x  + (size_t)batch * 2048 * 1024 + (size_t)mblk * 128 * 1024;
    const u16*   Wdb = Wd + (size_t)batch * 256 * 1024;
    const u16*   Wub = Wu + (size_t)batch * 1024 * 256;
    const float* bdb = bd + batch * 256;
    const float* bub = bu + batch * 1024;
    float*       ob  = out + (size_t)batch * 2048 * 1024 + (size_t)mblk * 128 * 1024;

    // ================= phase 1: R = relu(x @ Wd^T + bd), dbuf BK=64 ========
    const int wm1 = wave >> 2, wn1 = wave & 3;   // 2x4 over 128x256

    u16* const b0x = lds1;  u16* const b0w = lds1 + 8192;   // even iters
    u16* const b1x = lds0;  u16* const b1w = lds0 + 8192;   // odd iters

    // x staging geometry (2 slots/thread, 8-slot rows, 64-elem rows)
    const int xrow = tid >> 3, xsl = tid & 7;
    const int xdst0 = (xrow * 8 + (xsl ^ (xrow & 7))) * 8;  // swizzled LDS elems
    const int xdst1 = xdst0 + 4096;                          // row+64: same (row&7)
    // Wd staging: 4 gloads/thread; permuted global col (row&7 const over r)
    const int wrow  = tid >> 3;                              // + r*64
    const int wgcol = ((tid & 7) ^ ((tid >> 3) & 7)) * 8;

    f32x4 acc1[4][4] = {};

    // prologue: stage iter 0 into buf0
    {
        const float4 a0 = *(const float4*)(xb + (size_t)xrow * 1024 + xsl * 8);
        const float4 a1 = *(const float4*)(xb + (size_t)xrow * 1024 + xsl * 8 + 4);
        const float4 a2 = *(const float4*)(xb + (size_t)(xrow + 64) * 1024 + xsl * 8);
        const float4 a3 = *(const float4*)(xb + (size_t)(xrow + 64) * 1024 + xsl * 8 + 4);
        #pragma unroll
        for (int r = 0; r < 4; ++r)
            gload_lds16(Wdb + (size_t)(r * 64 + wrow) * 1024 + wgcol,
                        b0w + (size_t)(r * 512 + wave * 64) * 8);
        store8(b0x + xdst0, a0, a1);
        store8(b0x + xdst1, a2, a3);
    }
    __syncthreads();

    for (int it = 0; it < 16; ++it) {
        u16* cx = (it & 1) ? b1x : b0x;
        u16* cw = (it & 1) ? b1w : b0w;
        u16* nx = (it & 1) ? b0x : b1x;
        u16* nw = (it & 1) ? b0w : b1w;
        const int k1 = (it + 1) * 64;

        float4 a0, a1, a2, a3;
        if (it < 15) {
            a0 = *(const float4*)(xb + (size_t)xrow * 1024 + k1 + xsl * 8);
            a1 = *(const float4*)(xb + (size_t)xrow * 1024 + k1 + xsl * 8 + 4);
            a2 = *(const float4*)(xb + (size_t)(xrow + 64) * 1024 + k1 + xsl * 8);
            a3 = *(const float4*)(xb + (size_t)(xrow + 64) * 1024 + k1 + xsl * 8 + 4);
            #pragma unroll
            for (int r = 0; r < 4; ++r)
                gload_lds16(Wdb + (size_t)(r * 64 + wrow) * 1024 + k1 + wgcol,
                            nw + (size_t)(r * 512 + wave * 64) * 8);
        }

        #pragma unroll
        for (int kk = 0; kk < 64; kk += 32) {
            bf16x8 av[4], bv[4];
            #pragma unroll
            for (int mi = 0; mi < 4; ++mi)
                av[mi] = *(const bf16x8*)(cx + (wm1 * 64 + mi * 16 + rl) * 64
                                          + ((kk / 8 + quad) ^ rxl) * 8);
            #pragma unroll
            for (int ni = 0; ni < 4; ++ni)
                bv[ni] = *(const bf16x8*)(cw + (wn1 * 64 + ni * 16 + rl) * 64
                                          + ((kk / 8 + quad) ^ rxl) * 8);
            #pragma unroll
            for (int mi = 0; mi < 4; ++mi)
                #pragma unroll
                for (int ni = 0; ni < 4; ++ni)
                    acc1[mi][ni] = __builtin_amdgcn_mfma_f32_16x16x32_bf16(
                        av[mi], bv[ni], acc1[mi][ni], 0, 0, 0);
        }

        if (it < 15) { store8(nx + xdst0, a0, a1); store8(nx + xdst1, a2, a3); }
        __syncthreads();
    }

    // epilogue 1: bias + relu -> Rs (lds0), 32-slot rows, swizzled
    #pragma unroll
    for (int ni = 0; ni < 4; ++ni) {
        const int col = wn1 * 64 + ni * 16 + rl;
        const float bv = bdb[col];
        const int lbc = col >> 3, hi = lbc & 24, c7 = lbc & 7, cl = col & 7;
        #pragma unroll
        for (int mi = 0; mi < 4; ++mi)
            #pragma unroll
            for (int i = 0; i < 4; ++i) {
                const int row = wm1 * 64 + mi * 16 + quad * 4 + i;
                const int phys = hi | (c7 ^ (row & 7));
                lds0[row * 256 + phys * 8 + cl] =
                    f2bf(fmaxf(acc1[mi][ni][i] + bv, 0.0f));
            }
    }
    __syncthreads();   // Rs complete; LAST barrier in the kernel

    // ====== phase 2: out = x + R @ Wu^T + bu — BARRIER-FREE per wave =======
    // wave (wm2, wn2): rows wm2*64..+63, cols wn2*256..+255 in 16 sub-chunks
    const int wm2 = wave >> 2, wn2 = wave & 3;

    // hoist R A-fragments to registers: af[mi][t], 128 VGPRs
    bf16x8 af[4][8];
    #pragma unroll
    for (int mi = 0; mi < 4; ++mi) {
        const int rowb = (wm2 * 64 + mi * 16 + rl) * 256;
        #pragma unroll
        for (int t = 0; t < 8; ++t) {
            const int lb = t * 4 + quad;
            const int phys = (lb & 24) | ((lb & 7) ^ rxl);
            af[mi][t] = *(const bf16x8*)(lds0 + rowb + phys * 8);
        }
    }

    const u16* Wuw = Wub + (size_t)(wn2 * 256) * 256;  // this wave's col strip

    for (int c = 0; c < 16; ++c) {
        const int col0 = c * 16;
        const int colg = wn2 * 256 + col0 + rl;

        // B fragments straight from global (L2-hot): n=rl, k=t*32+quad*8+j
        bf16x8 bv[8];
        #pragma unroll
        for (int t = 0; t < 8; ++t)
            bv[t] = *(const bf16x8*)(Wuw + (size_t)(col0 + rl) * 256
                                     + t * 32 + quad * 8);

        // residual prefetch (issues early, overlaps MFMA)
        float xr[4][4];
        #pragma unroll
        for (int mi = 0; mi < 4; ++mi)
            #pragma unroll
            for (int i = 0; i < 4; ++i)
                xr[mi][i] = xb[(size_t)(wm2 * 64 + mi * 16 + quad * 4 + i) * 1024
                               + colg];

        f32x4 acc2[4] = {};
        #pragma unroll
        for (int t = 0; t < 8; ++t)
            #pragma unroll
            for (int mi = 0; mi < 4; ++mi)
                acc2[mi] = __builtin_amdgcn_mfma_f32_16x16x32_bf16(
                    af[mi][t], bv[t], acc2[mi], 0, 0, 0);

        const float buv = bub[colg];
        #pragma unroll
        for (int mi = 0; mi < 4; ++mi)
            #pragma unroll
            for (int i = 0; i < 4; ++i) {
                const int row = wm2 * 64 + mi * 16 + quad * 4 + i;
                ob[(size_t)row * 1024 + colg] = acc2[mi][i] + buv + xr[mi][i];
            }
    }
}

// ---------------------------------------------------------------------------
extern "C" void kernel_launch(void* const* d_in, const int* in_sizes, int n_in,
                              void* d_out, int out_size, void* d_ws, size_t ws_size,
                              hipStream_t stream) {
    const float* hidden = (const float*)d_in[0];   // (16, 2048, 1024) fp32
    const float* prob   = (const float*)d_in[1];   // (16, 8) fp32
    const float* w_down = (const float*)d_in[2];   // (8, 256, 1024) fp32
    const float* b_down = (const float*)d_in[3];   // (8, 256) fp32
    const float* w_up   = (const float*)d_in[4];   // (8, 1024, 256) fp32
    const float* b_up   = (const float*)d_in[5];   // (8, 1024) fp32
    float* out = (float*)d_out;                    // (16, 2048, 1024) fp32

    // workspace: merged weights (bf16) + biases (fp32), ~16.1 MB
    u16* Wd = (u16*)d_ws;                               // 16*256*1024 bf16
    u16* Wu = Wd + (size_t)16 * 256 * 1024;             // 16*1024*256 bf16
    float* bd = (float*)(Wu + (size_t)16 * 1024 * 256); // 16*256 f32
    float* bu = bd + 16 * 256;                          // 16*1024 f32

    merge_kernel<<<336, 256, 0, stream>>>(prob, w_down, b_down, w_up, b_up,
                                          Wd, Wu, bd, bu);

    fused_adapter<<<256, 512, 0, stream>>>(hidden, Wd, Wu, bd, bu, out);
}